// Round 5
// baseline (3427.903 us; speedup 1.0000x reference)
//
#include <hip/hip_runtime.h>
#include <hip/hip_bf16.h>
#include <cmath>

typedef unsigned short u16;
typedef __bf16 bf16_t;
typedef __bf16 bf16x8 __attribute__((ext_vector_type(8)));
typedef float f32x4 __attribute__((ext_vector_type(4)));

#define HDIM   768
#define NHEAD  12
#define HD     64
#define SEQ    1024
#define BATCH  2
#define NLAYER 12
#define FFI    3072
#define VOCAB  50257
#define NTOK   (BATCH*SEQ)
#define QKVW   2304   // packed q|k|v output width

__device__ inline u16 f2bf(float f) {
  bf16_t h = (bf16_t)f;                 // RNE fptrunc
  return __builtin_bit_cast(u16, h);
}

__device__ __forceinline__ void gl_lds16(const u16* g, u16* l) {
  // async global->LDS, 16B/lane; LDS dest = wave-uniform base + lane*16
  __builtin_amdgcn_global_load_lds(
      (const __attribute__((address_space(1))) unsigned int*)g,
      (__attribute__((address_space(3))) unsigned int*)l, 16, 0, 0);
}

// ---------------- batched NT GEMM: C[m,n] = sum_k A[m,k] * W[n,k] ----------------
// A bf16 via global_load_lds. W bf16 via global_load_lds, or fp32 (reg-staged + convert).
// Tile TMt x TNt, 4 waves in 2x2 grid (per-wave (TMt/2)x(TNt/2)).
// EPI: 0 = plain store (OT f32 or bf16)
//      2 = bf16( gelu(acc + bias[n]) )
//      3 = split-K residual: atomicAdd(C_f32, acc + bias[n] on first k-chunk)
// ksplit>1: blockIdx.z = K-chunk index (requires zdiv==1, K % (ksplit*BKK) == 0)
// swz!=0: 1-D grid of 6400; xcd=id&7 owns 50 contiguous N-panels (lm_head L2 locality)
#define BKK 64

template<typename WT, typename OT, int EPI, int TMt, int TNt>
__global__ __launch_bounds__(256, 2) void gemm_nt(
    const u16* __restrict__ A, const WT* __restrict__ W, OT* __restrict__ C,
    const float* __restrict__ bias,
    int M, int N, int K, int lda, int ldb, int ldc,
    long long aOut, long long aIn, long long bOut, long long bIn,
    long long cOut, long long cIn, int zdiv, int causal, int ksplit, int swz)
{
  constexpr int WMt = TMt / 2, WNt = TNt / 2;   // per-wave output
  constexpr int MI = WMt / 16, NJ = WNt / 16;   // 16x16 fragments per wave
  constexpr int ACH = TMt / 32;                 // 8-row staging chunks per wave
  constexpr int BCH = TNt / 32;

  __shared__ __align__(16) u16 sA[TMt * BKK];
  __shared__ __align__(16) u16 sB[TNt * BKK];

  int bx = blockIdx.x, by = blockIdx.y;
  if (swz) {
    // XCD-chunked remap: id%8 empirically selects the XCD; give each XCD a
    // contiguous span of N-panels so its L2 re-uses them. Bijective; guard tail.
    int id = blockIdx.x;
    int xcd = id & 7, j = id >> 3;
    bx = j & 15;                 // M-tile (gridM hardcoded 16: NTOK/128)
    by = xcd * 50 + (j >> 4);    // N-panel chunk of 50 per XCD
    if (by >= 393) return;
  }

  int z = blockIdx.z;
  if (zdiv > 1) {
    int zo = z / zdiv, zi = z - zo * zdiv;
    A += zo * aOut + zi * aIn;
    W += zo * bOut + zi * bIn;
    C += zo * cOut + zi * cIn;
  }
  int kt0 = 0, kend = K;
  if (ksplit > 1) {            // z indexes the K-chunk instead
    int kc = K / ksplit;
    kt0 = z * kc;
    kend = kt0 + kc;
  }
  int mt = bx * TMt;
  int nt = by * TNt;
  if (causal && nt > mt + (TMt - 1)) return;  // tile entirely above diagonal

  int t = threadIdx.x;
  int w = t >> 6, l = t & 63;
  int wm = (w >> 1) * WMt, wn = (w & 1) * WNt;
  int quad = l >> 4, mr = l & 15;

  int lrow = l >> 3;          // lane's row within 8-row staging chunk
  int lcol = (l & 7) * 8;     // lane's 8-elem k chunk

  // fp32-W staging pattern (register path)
  int arow = t >> 3, akc = (t & 7) * 8;

  f32x4 acc[MI][NJ] = {};

  for (int kt = kt0; kt < kend; kt += BKK) {
    #pragma unroll
    for (int i = 0; i < ACH; i++) {
      int row = w * (TMt / 4) + i * 8;      // wave-uniform LDS chunk base
      gl_lds16(A + (size_t)(mt + row + lrow) * lda + kt + lcol, &sA[row * BKK]);
    }
    if constexpr (sizeof(WT) == 2) {
      #pragma unroll
      for (int i = 0; i < BCH; i++) {
        int row = w * (TNt / 4) + i * 8;
        int gr = nt + row + lrow; if (gr >= N) gr = N - 1;   // per-lane clamp
        gl_lds16((const u16*)W + (size_t)gr * ldb + kt + lcol, &sB[row * BKK]);
      }
    } else {
      #pragma unroll
      for (int i = 0; i < BCH; i++) {
        int row = arow + i * 32;
        int gr = nt + row; if (gr >= N) gr = N - 1;
        const float* src = (const float*)W + (size_t)gr * ldb + kt + akc;
        float4 f0 = *(const float4*)(src);
        float4 f1 = *(const float4*)(src + 4);
        uint4 p;
        p.x = (unsigned)f2bf(f0.x) | ((unsigned)f2bf(f0.y) << 16);
        p.y = (unsigned)f2bf(f0.z) | ((unsigned)f2bf(f0.w) << 16);
        p.z = (unsigned)f2bf(f1.x) | ((unsigned)f2bf(f1.y) << 16);
        p.w = (unsigned)f2bf(f1.z) | ((unsigned)f2bf(f1.w) << 16);
        *(uint4*)(&sB[row * BKK + akc]) = p;
      }
    }
    __syncthreads();
    #pragma unroll
    for (int kk = 0; kk < BKK; kk += 32) {
      bf16x8 af[MI], bfr[NJ];
      #pragma unroll
      for (int i = 0; i < MI; i++)
        af[i] = *(const bf16x8*)(&sA[(wm + i * 16 + mr) * BKK + kk + quad * 8]);
      #pragma unroll
      for (int j = 0; j < NJ; j++)
        bfr[j] = *(const bf16x8*)(&sB[(wn + j * 16 + mr) * BKK + kk + quad * 8]);
      #pragma unroll
      for (int i = 0; i < MI; i++)
        #pragma unroll
        for (int j = 0; j < NJ; j++)
          acc[i][j] = __builtin_amdgcn_mfma_f32_16x16x32_bf16(af[i], bfr[j], acc[i][j], 0, 0, 0);
    }
    __syncthreads();
  }

  // C/D layout (m89-verified): col = lane&15, row = (lane>>4)*4 + reg
  #pragma unroll
  for (int i = 0; i < MI; i++)
    #pragma unroll
    for (int j = 0; j < NJ; j++)
      #pragma unroll
      for (int r = 0; r < 4; r++) {
        int gm = mt + wm + i * 16 + quad * 4 + r;
        int gn = nt + wn + j * 16 + mr;
        if (gn < N) {
          float v = acc[i][j][r];
          size_t idx = (size_t)gm * ldc + gn;
          if constexpr (EPI == 3) {
            float add = v + (kt0 == 0 ? bias[gn] : 0.0f);
            atomicAdd(&((float*)C)[idx], add);
          } else if constexpr (EPI == 2) {
            float u = v + bias[gn];
            float g = 0.5f * u * (1.0f + erff(u * 0.70710678118654752f));
            C[idx] = (OT)f2bf(g);
          } else {
            if constexpr (sizeof(OT) == 2) C[idx] = f2bf(v);
            else                           C[idx] = v;
          }
        }
      }
}

// ---------------- weight fp32 -> bf16 pre-conversion (8 elems/thread, guarded) ----------------
__global__ __launch_bounds__(256) void cvt_w(
    const float* __restrict__ src, u16* __restrict__ dst,
    long long srcLs, long long dstLs, long long perL, long long total)
{
  long long i8 = ((long long)blockIdx.x * 256 + threadIdx.x) * 8;
  if (i8 >= total) return;
  long long l = i8 / perL;
  long long r = i8 - l * perL;
  const float4* s4 = (const float4*)(src + l * srcLs + r);
  float4 f0 = s4[0], f1 = s4[1];
  uint4 p;
  p.x = (unsigned)f2bf(f0.x) | ((unsigned)f2bf(f0.y) << 16);
  p.y = (unsigned)f2bf(f0.z) | ((unsigned)f2bf(f0.w) << 16);
  p.z = (unsigned)f2bf(f1.x) | ((unsigned)f2bf(f1.y) << 16);
  p.w = (unsigned)f2bf(f1.z) | ((unsigned)f2bf(f1.w) << 16);
  *(uint4*)(dst + l * dstLs + r) = p;
}

// ---------------- LayerNorm row kernel: fp32 in -> bf16 out ----------------
__global__ __launch_bounds__(256) void ln_bf16(
    const float* __restrict__ x, const float* __restrict__ w,
    const float* __restrict__ b, u16* __restrict__ out)
{
  __shared__ float redA[4], redB[4];
  int row = blockIdx.x;
  const float* xr = x + (size_t)row * HDIM;
  int t = threadIdx.x;
  float v0 = xr[t], v1 = xr[t + 256], v2 = xr[t + 512];
  float s  = v0 + v1 + v2;
  float s2 = v0 * v0 + v1 * v1 + v2 * v2;
  #pragma unroll
  for (int o = 32; o > 0; o >>= 1) { s += __shfl_xor(s, o); s2 += __shfl_xor(s2, o); }
  if ((t & 63) == 0) { redA[t >> 6] = s; redB[t >> 6] = s2; }
  __syncthreads();
  float S  = redA[0] + redA[1] + redA[2] + redA[3];
  float S2 = redB[0] + redB[1] + redB[2] + redB[3];
  float mean = S * (1.0f / HDIM);
  float var  = S2 * (1.0f / HDIM) - mean * mean;
  float rstd = rsqrtf(var + 1e-5f);
  u16* orow = out + (size_t)row * HDIM;
  orow[t]       = f2bf((v0 - mean) * rstd * w[t]       + b[t]);
  orow[t + 256] = f2bf((v1 - mean) * rstd * w[t + 256] + b[t + 256]);
  orow[t + 512] = f2bf((v2 - mean) * rstd * w[t + 512] + b[t + 512]);
}

// ---------------- softmax: scale + causal + pad mask, bf16 scores -> bf16 P ----------------
// vectorized: each thread owns 4 contiguous j (ushort4 / int4 loads, ushort4 store)
__global__ __launch_bounds__(256) void softmax_causal(
    const u16* __restrict__ scores, u16* __restrict__ P,
    const int* __restrict__ amask)
{
  __shared__ float red[4];
  int row = blockIdx.x;            // z*SEQ + qi, z = b*NHEAD+h
  int z  = row >> 10;
  int qi = row & (SEQ - 1);
  int b  = z / NHEAD;
  const u16* s = scores + (size_t)row * SEQ;
  u16* p = P + (size_t)row * SEQ;
  int t = threadIdx.x;
  int j0 = t * 4;
  ushort4 sv = *(const ushort4*)(s + j0);          // garbage above diagonal: never used
  int4    mv = *(const int4*)(amask + b * SEQ + j0);
  u16 sa[4] = {sv.x, sv.y, sv.z, sv.w};
  int ma[4] = {mv.x, mv.y, mv.z, mv.w};
  float vals[4];
  float mx = -3.4e38f;
  #pragma unroll
  for (int i = 0; i < 4; i++) {
    float v = -1e9f;
    if (j0 + i <= qi && ma[i] != 0)
      v = (float)__builtin_bit_cast(bf16_t, sa[i]) * 0.125f;   // 1/sqrt(64)
    vals[i] = v;
    mx = fmaxf(mx, v);
  }
  #pragma unroll
  for (int o = 32; o > 0; o >>= 1) mx = fmaxf(mx, __shfl_xor(mx, o));
  if ((t & 63) == 0) red[t >> 6] = mx;
  __syncthreads();
  mx = fmaxf(fmaxf(red[0], red[1]), fmaxf(red[2], red[3]));
  float e[4]; float sum = 0.0f;
  #pragma unroll
  for (int i = 0; i < 4; i++) { e[i] = expf(vals[i] - mx); sum += e[i]; }
  #pragma unroll
  for (int o = 32; o > 0; o >>= 1) sum += __shfl_xor(sum, o);
  __syncthreads();
  if ((t & 63) == 0) red[t >> 6] = sum;
  __syncthreads();
  float inv = 1.0f / (red[0] + red[1] + red[2] + red[3]);
  ushort4 ov;
  ov.x = f2bf(e[0] * inv); ov.y = f2bf(e[1] * inv);
  ov.z = f2bf(e[2] * inv); ov.w = f2bf(e[3] * inv);
  *(ushort4*)(p + j0) = ov;
}

// ---------------- misc ----------------
__global__ void embed_k(const int* __restrict__ ids, const float* __restrict__ tok,
                        const float* __restrict__ pos, float* __restrict__ x)
{
  int tkn = blockIdx.x;                 // 192 threads: one float4 each (768 f32/row)
  int sidx = tkn & (SEQ - 1);
  int id = ids[tkn];
  int t = threadIdx.x;
  float4 a = ((const float4*)tok)[(size_t)id * 192 + t];
  float4 b = ((const float4*)pos)[(size_t)sidx * 192 + t];
  float4 o = {a.x + b.x, a.y + b.y, a.z + b.z, a.w + b.w};
  ((float4*)x)[(size_t)tkn * 192 + t] = o;
}

// tiled 64x64 transpose of the V slice of qkv:  vT[z,d,s] = qkv[b*SEQ+s, 1536 + h*64 + d]
__global__ __launch_bounds__(256) void transpose_v(const u16* __restrict__ qkv, u16* __restrict__ vT)
{
  __shared__ u16 tile[64][68];
  int z = blockIdx.y;                   // b*NH + h
  int s0 = blockIdx.x * 64;
  int b = z / NHEAD, hh = z - b * NHEAD;
  const u16* src = qkv + (size_t)(b * SEQ + s0) * QKVW + 1536 + hh * HD;
  int t = threadIdx.x;
  int c4 = (t & 15) * 4, r0 = t >> 4;
  #pragma unroll
  for (int i = 0; i < 4; i++) {
    int row = r0 + i * 16;
    *(uint2*)(&tile[row][c4]) = *(const uint2*)(src + (size_t)row * QKVW + c4);
  }
  __syncthreads();
  u16* dst = vT + (size_t)z * HD * SEQ + s0;
  #pragma unroll
  for (int i = 0; i < 4; i++) {
    int d = r0 + i * 16;
    ushort4 o;
    o.x = tile[c4 + 0][d];
    o.y = tile[c4 + 1][d];
    o.z = tile[c4 + 2][d];
    o.w = tile[c4 + 3][d];
    *(ushort4*)(dst + (size_t)d * SEQ + c4) = o;
  }
}

// ---------------- driver ----------------
extern "C" void kernel_launch(void* const* d_in, const int* in_sizes, int n_in,
                              void* d_out, int out_size, void* d_ws, size_t ws_size,
                              hipStream_t stream)
{
  const int*   ids   = (const int*)d_in[0];
  const int*   amask = (const int*)d_in[1];
  const float* tok   = (const float*)d_in[2];
  const float* pos   = (const float*)d_in[3];
  const float* ln1w  = (const float*)d_in[4];
  const float* ln1b  = (const float*)d_in[5];
  const float* qw    = (const float*)d_in[6];
  const float* kw    = (const float*)d_in[7];
  const float* vw    = (const float*)d_in[8];
  const float* ow    = (const float*)d_in[9];
  const float* ob    = (const float*)d_in[10];
  const float* ln2w  = (const float*)d_in[11];
  const float* ln2b  = (const float*)d_in[12];
  const float* w1    = (const float*)d_in[13];
  const float* b1    = (const float*)d_in[14];
  const float* w2    = (const float*)d_in[15];
  const float* b2    = (const float*)d_in[16];
  const float* lnfw  = (const float*)d_in[17];
  const float* lnfb  = (const float*)d_in[18];
  const float* lmw   = (const float*)d_in[19];

  // ---- workspace layout (bytes), core = 37.75 MB ----
  char* ws = (char*)d_ws;
  float* x    = (float*)(ws);                   // 2048x768 f32        6,291,456
  u16*   h    = (u16*)  (ws + 6291456);         // 2048x768 bf16       3,145,728
  u16*   qkv  = (u16*)  (ws + 9437184);         // 2048x2304 bf16      9,437,184
  u16*   vT   = (u16*)  (ws + 18874368);        // [B,NH,HD,S] bf16    3,145,728
  u16*   ab   = (u16*)  (ws + 22020096);        // attn out bf16       3,145,728
  u16*   ffb  = (u16*)  (ws + 25165824);        // 2048x3072 bf16     12,582,912 -> end 37,748,736
  // optional lm_head bf16 weight cache (cannot live in d_out: final GEMM writes
  // ALL of d_out while reading its B operand -> would race)
  u16*   wlm  = (u16*)  (ws + 37748736);        // 50257x768 bf16     77,194,752 -> end 114,943,488
  bool lmbf = ws_size >= (size_t)114943488;

  // ---- d_out scratch (411.7 MB total; all dead before final lm_head write) ----
  u16* scores = (u16*)d_out;                          // 24x1024x1024 bf16 =  50,331,648
  u16* Pm     = (u16*)((char*)d_out + 50331648);      // 24x1024x1024 bf16 =  50,331,648
  u16* wqkv   = (u16*)((char*)d_out + 100663296);     // 12 x 2304x768 bf16
  u16* wob    = wqkv + (size_t)NLAYER * QKVW * HDIM;  // 12 x 768x768
  u16* w1b    = wob  + (size_t)NLAYER * HDIM * HDIM;  // 12 x 3072x768
  u16* w2b    = w1b  + (size_t)NLAYER * FFI  * HDIM;  // 12 x 768x3072  -> end 270,532,608

  // ---- one-shot weight conversion fp32 -> bf16 (packed QKV), 8 elems/thread ----
  cvt_w<<<3456,  256, 0, stream>>>(qw, wqkv,           589824, 1769472, 589824, 7077888LL);
  cvt_w<<<3456,  256, 0, stream>>>(kw, wqkv + 589824,  589824, 1769472, 589824, 7077888LL);
  cvt_w<<<3456,  256, 0, stream>>>(vw, wqkv + 1179648, 589824, 1769472, 589824, 7077888LL);
  cvt_w<<<3456,  256, 0, stream>>>(ow, wob,            589824, 589824,  589824, 7077888LL);
  cvt_w<<<13824, 256, 0, stream>>>(w1, w1b,            2359296, 2359296, 2359296, 28311552LL);
  cvt_w<<<13824, 256, 0, stream>>>(w2, w2b,            2359296, 2359296, 2359296, 28311552LL);
  if (lmbf)
    cvt_w<<<18847, 256, 0, stream>>>(lmw, wlm, 0, 0, 38597376LL, 38597376LL);

  embed_k<<<NTOK, 192, 0, stream>>>(ids, tok, pos, x);

  for (int l = 0; l < NLAYER; l++) {
    ln_bf16<<<NTOK, 256, 0, stream>>>(x, ln1w + l * HDIM, ln1b + l * HDIM, h);

    // fused QKV: [2048,768] @ [2304,768]^T -> qkv [2048,2304]
    gemm_nt<u16, u16, 0, 128, 128><<<dim3(16, 18), 256, 0, stream>>>(
        h, wqkv + (size_t)l * QKVW * HDIM, qkv, nullptr,
        NTOK, QKVW, HDIM, HDIM, HDIM, QKVW, 0, 0, 0, 0, 0, 0, 1, 0, 1, 0);

    transpose_v<<<dim3(16, BATCH * NHEAD), 256, 0, stream>>>(qkv, vT);

    // scores[z,i,j] = q . k  (bf16 out; scale applied in softmax)
    gemm_nt<u16, u16, 0, 128, 128><<<dim3(8, 8, BATCH * NHEAD), 256, 0, stream>>>(
        qkv, qkv + 768, scores, nullptr,
        SEQ, SEQ, HD, QKVW, QKVW, SEQ,
        (long long)SEQ * QKVW, HD, (long long)SEQ * QKVW, HD,
        (long long)NHEAD * SEQ * SEQ, (long long)SEQ * SEQ, NHEAD, 1, 1, 0);

    softmax_causal<<<BATCH * NHEAD * SEQ, 256, 0, stream>>>(scores, Pm, amask);

    // a[b,i,h*64+d] = sum_j P[z,i,j] * vT[z,d,j]   (64x64 tiles: N=64 exact, 384 blocks)
    gemm_nt<u16, u16, 0, 64, 64><<<dim3(16, 1, BATCH * NHEAD), 256, 0, stream>>>(
        Pm, vT, ab, nullptr,
        SEQ, HD, SEQ, SEQ, SEQ, HDIM,
        (long long)NHEAD * SEQ * SEQ, (long long)SEQ * SEQ,
        (long long)NHEAD * HD * SEQ, (long long)HD * SEQ,
        (long long)SEQ * HDIM, HD, NHEAD, 0, 1, 0);

    // proj, split-K=2, fused bias + residual: x += ab @ ow^T + ob  (atomic f32)
    gemm_nt<u16, float, 3, 128, 128><<<dim3(16, 6, 2), 256, 0, stream>>>(
        ab, wob + (size_t)l * HDIM * HDIM, x, ob + l * HDIM,
        NTOK, HDIM, HDIM, HDIM, HDIM, HDIM, 0, 0, 0, 0, 0, 0, 1, 0, 2, 0);

    ln_bf16<<<NTOK, 256, 0, stream>>>(x, ln2w + l * HDIM, ln2b + l * HDIM, h);

    // FF1 with fused bias + exact gelu -> bf16
    gemm_nt<u16, u16, 2, 128, 128><<<dim3(16, 24), 256, 0, stream>>>(
        h, w1b + (size_t)l * FFI * HDIM, ffb, b1 + l * FFI,
        NTOK, FFI, HDIM, HDIM, HDIM, FFI, 0, 0, 0, 0, 0, 0, 1, 0, 1, 0);

    // FF2, split-K=4, fused bias + residual: x += ffb @ w2^T + b2  (atomic f32)
    gemm_nt<u16, float, 3, 128, 128><<<dim3(16, 6, 4), 256, 0, stream>>>(
        ffb, w2b + (size_t)l * HDIM * FFI, x, b2 + l * HDIM,
        NTOK, HDIM, FFI, FFI, FFI, HDIM, 0, 0, 0, 0, 0, 0, 1, 0, 4, 0);
  }

  ln_bf16<<<NTOK, 256, 0, stream>>>(x, lnfw, lnfb, h);
  if (lmbf) {
    // bf16-cached lm_head weights + XCD-chunked swizzle (1-D grid, 50 panels/XCD)
    gemm_nt<u16, float, 0, 128, 128><<<6400, 256, 0, stream>>>(
        h, wlm, (float*)d_out, nullptr,
        NTOK, VOCAB, HDIM, HDIM, HDIM, VOCAB, 0, 0, 0, 0, 0, 0, 1, 0, 1, 1);
  } else {
    // fallback: fp32 weights, reg-staged + in-loop convert (same swizzle)
    gemm_nt<float, float, 0, 128, 128><<<6400, 256, 0, stream>>>(
        h, lmw, (float*)d_out, nullptr,
        NTOK, VOCAB, HDIM, HDIM, HDIM, VOCAB, 0, 0, 0, 0, 0, 0, 1, 0, 1, 1);
  }
}

// Round 7
// 3424.343 us; speedup vs baseline: 1.0010x; 1.0010x over previous
//
#include <hip/hip_runtime.h>
#include <hip/hip_bf16.h>
#include <cmath>

typedef unsigned short u16;
typedef __bf16 bf16_t;
typedef __bf16 bf16x8 __attribute__((ext_vector_type(8)));
typedef float f32x4 __attribute__((ext_vector_type(4)));

#define HDIM   768
#define NHEAD  12
#define HD     64
#define SEQ    1024
#define BATCH  2
#define NLAYER 12
#define FFI    3072
#define VOCAB  50257
#define NTOK   (BATCH*SEQ)
#define QKVW   2304   // packed q|k|v output width

__device__ inline u16 f2bf(float f) {
  bf16_t h = (bf16_t)f;                 // RNE fptrunc
  return __builtin_bit_cast(u16, h);
}

__device__ __forceinline__ void gl_lds16(const u16* g, u16* l) {
  // async global->LDS, 16B/lane; LDS dest = wave-uniform base + lane*16
  __builtin_amdgcn_global_load_lds(
      (const __attribute__((address_space(1))) unsigned int*)g,
      (__attribute__((address_space(3))) unsigned int*)l, 16, 0, 0);
}

// ---------------- batched NT GEMM: C[m,n] = sum_k A[m,k] * W[n,k] ----------------
// A bf16 via global_load_lds. W bf16 via global_load_lds, or fp32 (reg-staged + convert).
// Tile TMt x TNt, 4 waves in 2x2 grid (per-wave (TMt/2)x(TNt/2)).
// EPI: 0 = plain store (OT f32 or bf16)
//      2 = bf16( gelu(acc + bias[n]) )
//      3 = split-K residual: atomicAdd(C_f32, acc + bias[n] on first k-chunk)
// ksplit>1: blockIdx.z = K-chunk index (requires zdiv==1, K % (ksplit*BKK) == 0)
// swz!=0: 1-D grid of 6400; xcd=id&7 owns 50 contiguous N-panels (lm_head L2 locality)
#define BKK 64

template<typename WT, typename OT, int EPI, int TMt, int TNt>
__global__ __launch_bounds__(256, 2) void gemm_nt(
    const u16* __restrict__ A, const WT* __restrict__ W, OT* __restrict__ C,
    const float* __restrict__ bias,
    int M, int N, int K, int lda, int ldb, int ldc,
    long long aOut, long long aIn, long long bOut, long long bIn,
    long long cOut, long long cIn, int zdiv, int causal, int ksplit, int swz)
{
  constexpr int WMt = TMt / 2, WNt = TNt / 2;   // per-wave output
  constexpr int MI = WMt / 16, NJ = WNt / 16;   // 16x16 fragments per wave
  constexpr int ACH = TMt / 32;                 // 8-row staging chunks per wave
  constexpr int BCH = TNt / 32;

  __shared__ __align__(16) u16 sA[TMt * BKK];
  __shared__ __align__(16) u16 sB[TNt * BKK];

  int bx = blockIdx.x, by = blockIdx.y;
  if (swz) {
    // XCD-chunked remap: id%8 empirically selects the XCD; give each XCD a
    // contiguous span of N-panels so its L2 re-uses them. Bijective; guard tail.
    int id = blockIdx.x;
    int xcd = id & 7, j = id >> 3;
    bx = j & 15;                 // M-tile (gridM hardcoded 16: NTOK/128)
    by = xcd * 50 + (j >> 4);    // N-panel chunk of 50 per XCD
    if (by >= 393) return;
  }

  int z = blockIdx.z;
  if (zdiv > 1) {
    int zo = z / zdiv, zi = z - zo * zdiv;
    A += zo * aOut + zi * aIn;
    W += zo * bOut + zi * bIn;
    C += zo * cOut + zi * cIn;
  }
  int kt0 = 0, kend = K;
  if (ksplit > 1) {            // z indexes the K-chunk instead
    int kc = K / ksplit;
    kt0 = z * kc;
    kend = kt0 + kc;
  }
  int mt = bx * TMt;
  int nt = by * TNt;
  if (causal && nt > mt + (TMt - 1)) return;  // tile entirely above diagonal

  int t = threadIdx.x;
  int w = t >> 6, l = t & 63;
  int wm = (w >> 1) * WMt, wn = (w & 1) * WNt;
  int quad = l >> 4, mr = l & 15;

  int lrow = l >> 3;          // lane's row within 8-row staging chunk
  int lcol = (l & 7) * 8;     // lane's 8-elem k chunk

  // fp32-W staging pattern (register path)
  int arow = t >> 3, akc = (t & 7) * 8;

  f32x4 acc[MI][NJ] = {};

  for (int kt = kt0; kt < kend; kt += BKK) {
    #pragma unroll
    for (int i = 0; i < ACH; i++) {
      int row = w * (TMt / 4) + i * 8;      // wave-uniform LDS chunk base
      gl_lds16(A + (size_t)(mt + row + lrow) * lda + kt + lcol, &sA[row * BKK]);
    }
    if constexpr (sizeof(WT) == 2) {
      #pragma unroll
      for (int i = 0; i < BCH; i++) {
        int row = w * (TNt / 4) + i * 8;
        int gr = nt + row + lrow; if (gr >= N) gr = N - 1;   // per-lane clamp
        gl_lds16((const u16*)W + (size_t)gr * ldb + kt + lcol, &sB[row * BKK]);
      }
    } else {
      #pragma unroll
      for (int i = 0; i < BCH; i++) {
        int row = arow + i * 32;
        int gr = nt + row; if (gr >= N) gr = N - 1;
        const float* src = (const float*)W + (size_t)gr * ldb + kt + akc;
        float4 f0 = *(const float4*)(src);
        float4 f1 = *(const float4*)(src + 4);
        uint4 p;
        p.x = (unsigned)f2bf(f0.x) | ((unsigned)f2bf(f0.y) << 16);
        p.y = (unsigned)f2bf(f0.z) | ((unsigned)f2bf(f0.w) << 16);
        p.z = (unsigned)f2bf(f1.x) | ((unsigned)f2bf(f1.y) << 16);
        p.w = (unsigned)f2bf(f1.z) | ((unsigned)f2bf(f1.w) << 16);
        *(uint4*)(&sB[row * BKK + akc]) = p;
      }
    }
    __syncthreads();
    #pragma unroll
    for (int kk = 0; kk < BKK; kk += 32) {
      bf16x8 af[MI], bfr[NJ];
      #pragma unroll
      for (int i = 0; i < MI; i++)
        af[i] = *(const bf16x8*)(&sA[(wm + i * 16 + mr) * BKK + kk + quad * 8]);
      #pragma unroll
      for (int j = 0; j < NJ; j++)
        bfr[j] = *(const bf16x8*)(&sB[(wn + j * 16 + mr) * BKK + kk + quad * 8]);
      #pragma unroll
      for (int i = 0; i < MI; i++)
        #pragma unroll
        for (int j = 0; j < NJ; j++)
          acc[i][j] = __builtin_amdgcn_mfma_f32_16x16x32_bf16(af[i], bfr[j], acc[i][j], 0, 0, 0);
    }
    __syncthreads();
  }

  // C/D layout (m89-verified): col = lane&15, row = (lane>>4)*4 + reg
  #pragma unroll
  for (int i = 0; i < MI; i++)
    #pragma unroll
    for (int j = 0; j < NJ; j++)
      #pragma unroll
      for (int r = 0; r < 4; r++) {
        int gm = mt + wm + i * 16 + quad * 4 + r;
        int gn = nt + wn + j * 16 + mr;
        if (gn < N) {
          float v = acc[i][j][r];
          size_t idx = (size_t)gm * ldc + gn;
          if constexpr (EPI == 3) {
            float add = v + (kt0 == 0 ? bias[gn] : 0.0f);
            atomicAdd(&((float*)C)[idx], add);
          } else if constexpr (EPI == 2) {
            float u = v + bias[gn];
            float g = 0.5f * u * (1.0f + erff(u * 0.70710678118654752f));
            C[idx] = (OT)f2bf(g);
          } else {
            if constexpr (sizeof(OT) == 2) C[idx] = f2bf(v);
            else                           C[idx] = v;
          }
        }
      }
}

// ---------------- fused flash attention ----------------
// grid (16, 24): blockIdx.x = 64-row Q-block, blockIdx.y = z = b*NHEAD+h.
// Per block: Q[64][64] staged once; loop 64-wide K/V tiles with online softmax.
// Wave w owns Q-rows [w*16, w*16+16); all 64 kv-cols / d-cols (MI=1, NJ=4).
// S[m,kv] = sum_d Q[m,d]*K[kv,d]  (NT form: K needs no transpose).
// V transposed LDS->LDS (verified transpose_v pattern) for the PV NT-GEMM.
// sPV time-shares: V-landing tile [64][68] then P[64][64]; live ranges
// separated by the barriers (tileV dead after transpose barrier, P written after).
__global__ __launch_bounds__(256, 2) void flash_attn(
    const u16* __restrict__ qkv, u16* __restrict__ ab, const int* __restrict__ amask)
{
  __shared__ __align__(16) u16 sQ[64 * 64];
  __shared__ __align__(16) u16 sK[64 * 64];
  __shared__ __align__(16) u16 sVT[64 * 72];     // [d][kv], pad 72 vs 64: 2-way banks
  __shared__ __align__(16) u16 sPV[64 * 68];     // tileV[64][68]  <->  P[64][64]
  __shared__ u16 s_am[SEQ];

  int MT = blockIdx.x * 64;
  int z  = blockIdx.y;
  int b  = z / NHEAD, h = z - b * NHEAD;
  const u16* qbase = qkv + (size_t)(b * SEQ) * QKVW + h * HD;
  const u16* kbase = qbase + 768;
  const u16* vbase = qbase + 1536;

  int t = threadIdx.x;
  int w = t >> 6, l = t & 63;
  int quad = l >> 4, mr = l & 15;
  int lrow = l >> 3, lcol = (l & 7) * 8;
  int wm = w * 16;
  int c4 = (t & 15) * 4, r0 = t >> 4;

  // stage Q rows MT..MT+63 (per wave: 2 chunks of 8 rows)
  #pragma unroll
  for (int i = 0; i < 2; i++) {
    int row = w * 16 + i * 8;
    gl_lds16(qbase + (size_t)(MT + row + lrow) * QKVW + lcol, &sQ[row * 64]);
  }
  // stage pad-mask flags for this batch row
  {
    int4 mv = *(const int4*)(amask + b * SEQ + t * 4);
    s_am[t * 4 + 0] = (u16)(mv.x != 0);
    s_am[t * 4 + 1] = (u16)(mv.y != 0);
    s_am[t * 4 + 2] = (u16)(mv.z != 0);
    s_am[t * 4 + 3] = (u16)(mv.w != 0);
  }

  f32x4 oacc[4] = {};
  float mrun[4] = {-3.0e38f, -3.0e38f, -3.0e38f, -3.0e38f};
  float lrun[4] = {};

  for (int jt = 0; jt <= MT; jt += 64) {
    // A: issue K tile gl_lds + V tile register loads
    #pragma unroll
    for (int i = 0; i < 2; i++) {
      int row = w * 16 + i * 8;
      gl_lds16(kbase + (size_t)(jt + row + lrow) * QKVW + lcol, &sK[row * 64]);
    }
    uint2 vr[4];
    #pragma unroll
    for (int i = 0; i < 4; i++)
      vr[i] = *(const uint2*)(vbase + (size_t)(jt + r0 + i * 16) * QKVW + c4);
    __syncthreads();   // all prev-iter PV done (sPV free); K landed; V regs ready
    // D: V regs -> landing tile (padded 68)
    #pragma unroll
    for (int i = 0; i < 4; i++)
      *(uint2*)(&sPV[(r0 + i * 16) * 68 + c4]) = vr[i];
    __syncthreads();
    // F1: S = Q . K^T   (MI=1, NJ=4)
    f32x4 sacc[4] = {};
    #pragma unroll
    for (int kk = 0; kk < 64; kk += 32) {
      bf16x8 af = *(const bf16x8*)(&sQ[(wm + mr) * 64 + kk + quad * 8]);
      #pragma unroll
      for (int j = 0; j < 4; j++) {
        bf16x8 bf = *(const bf16x8*)(&sK[(j * 16 + mr) * 64 + kk + quad * 8]);
        sacc[j] = __builtin_amdgcn_mfma_f32_16x16x32_bf16(af, bf, sacc[j], 0, 0, 0);
      }
    }
    // F2: transpose landing tile -> sVT[d][kv]
    #pragma unroll
    for (int i = 0; i < 4; i++) {
      int d = r0 + i * 16;
      ushort4 o;
      o.x = sPV[(c4 + 0) * 68 + d];
      o.y = sPV[(c4 + 1) * 68 + d];
      o.z = sPV[(c4 + 2) * 68 + d];
      o.w = sPV[(c4 + 3) * 68 + d];
      *(ushort4*)(&sVT[d * 72 + c4]) = o;
    }
    __syncthreads();   // sVT ready; landing tile dead -> P may overwrite sPV
    // H: online masked softmax (scale, causal+pad mask, running max/sum)
    float sv[4][4];
    float mx[4] = {-3.0e38f, -3.0e38f, -3.0e38f, -3.0e38f};
    #pragma unroll
    for (int j = 0; j < 4; j++) {
      int colg = jt + j * 16 + mr;
      bool am = s_am[colg] != 0;
      #pragma unroll
      for (int r = 0; r < 4; r++) {
        int rowg = MT + wm + quad * 4 + r;
        float v = (am && colg <= rowg) ? sacc[j][r] * 0.125f : -1e9f;
        sv[j][r] = v;
        mx[r] = fmaxf(mx[r], v);
      }
    }
    #pragma unroll
    for (int off = 8; off > 0; off >>= 1)
      #pragma unroll
      for (int r = 0; r < 4; r++) mx[r] = fmaxf(mx[r], __shfl_xor(mx[r], off));
    float alpha[4], lsum[4];
    #pragma unroll
    for (int r = 0; r < 4; r++) {
      float mn = fmaxf(mrun[r], mx[r]);
      alpha[r] = expf(mrun[r] - mn);
      mrun[r] = mn;
      lsum[r] = 0.0f;
    }
    #pragma unroll
    for (int j = 0; j < 4; j++)
      #pragma unroll
      for (int r = 0; r < 4; r++) {
        float p = expf(sv[j][r] - mrun[r]);
        lsum[r] += p;
        sPV[(wm + quad * 4 + r) * 64 + j * 16 + mr] = f2bf(p);   // P, own-wave rows
      }
    #pragma unroll
    for (int off = 8; off > 0; off >>= 1)
      #pragma unroll
      for (int r = 0; r < 4; r++) lsum[r] += __shfl_xor(lsum[r], off);
    #pragma unroll
    for (int r = 0; r < 4; r++) {
      lrun[r] = lrun[r] * alpha[r] + lsum[r];
      #pragma unroll
      for (int j = 0; j < 4; j++) oacc[j][r] *= alpha[r];
    }
    // J: O += P . V^T   (reads own-wave P rows + shared sVT; no barrier needed)
    #pragma unroll
    for (int kk = 0; kk < 64; kk += 32) {
      bf16x8 af = *(const bf16x8*)(&sPV[(wm + mr) * 64 + kk + quad * 8]);
      #pragma unroll
      for (int j = 0; j < 4; j++) {
        bf16x8 bf = *(const bf16x8*)(&sVT[(j * 16 + mr) * 72 + kk + quad * 8]);
        oacc[j] = __builtin_amdgcn_mfma_f32_16x16x32_bf16(af, bf, oacc[j], 0, 0, 0);
      }
    }
  }
  // epilogue: normalize by running sum, write bf16
  u16* orow = ab + (size_t)(b * SEQ + MT) * HDIM + h * HD;
  #pragma unroll
  for (int r = 0; r < 4; r++) {
    float inv = 1.0f / lrun[r];
    int rowl = wm + quad * 4 + r;
    #pragma unroll
    for (int j = 0; j < 4; j++)
      orow[(size_t)rowl * HDIM + j * 16 + mr] = f2bf(oacc[j][r] * inv);
  }
}

// ---------------- weight fp32 -> bf16 pre-conversion (8 elems/thread, guarded) ----------------
__global__ __launch_bounds__(256) void cvt_w(
    const float* __restrict__ src, u16* __restrict__ dst,
    long long srcLs, long long dstLs, long long perL, long long total)
{
  long long i8 = ((long long)blockIdx.x * 256 + threadIdx.x) * 8;
  if (i8 >= total) return;
  long long l = i8 / perL;
  long long r = i8 - l * perL;
  const float4* s4 = (const float4*)(src + l * srcLs + r);
  float4 f0 = s4[0], f1 = s4[1];
  uint4 p;
  p.x = (unsigned)f2bf(f0.x) | ((unsigned)f2bf(f0.y) << 16);
  p.y = (unsigned)f2bf(f0.z) | ((unsigned)f2bf(f0.w) << 16);
  p.z = (unsigned)f2bf(f1.x) | ((unsigned)f2bf(f1.y) << 16);
  p.w = (unsigned)f2bf(f1.z) | ((unsigned)f2bf(f1.w) << 16);
  *(uint4*)(dst + l * dstLs + r) = p;
}

// ---------------- LayerNorm row kernel: fp32 in -> bf16 out ----------------
__global__ __launch_bounds__(256) void ln_bf16(
    const float* __restrict__ x, const float* __restrict__ w,
    const float* __restrict__ b, u16* __restrict__ out)
{
  __shared__ float redA[4], redB[4];
  int row = blockIdx.x;
  const float* xr = x + (size_t)row * HDIM;
  int t = threadIdx.x;
  float v0 = xr[t], v1 = xr[t + 256], v2 = xr[t + 512];
  float s  = v0 + v1 + v2;
  float s2 = v0 * v0 + v1 * v1 + v2 * v2;
  #pragma unroll
  for (int o = 32; o > 0; o >>= 1) { s += __shfl_xor(s, o); s2 += __shfl_xor(s2, o); }
  if ((t & 63) == 0) { redA[t >> 6] = s; redB[t >> 6] = s2; }
  __syncthreads();
  float S  = redA[0] + redA[1] + redA[2] + redA[3];
  float S2 = redB[0] + redB[1] + redB[2] + redB[3];
  float mean = S * (1.0f / HDIM);
  float var  = S2 * (1.0f / HDIM) - mean * mean;
  float rstd = rsqrtf(var + 1e-5f);
  u16* orow = out + (size_t)row * HDIM;
  orow[t]       = f2bf((v0 - mean) * rstd * w[t]       + b[t]);
  orow[t + 256] = f2bf((v1 - mean) * rstd * w[t + 256] + b[t + 256]);
  orow[t + 512] = f2bf((v2 - mean) * rstd * w[t + 512] + b[t + 512]);
}

// ---------------- misc ----------------
__global__ void embed_k(const int* __restrict__ ids, const float* __restrict__ tok,
                        const float* __restrict__ pos, float* __restrict__ x)
{
  int tkn = blockIdx.x;                 // 192 threads: one float4 each (768 f32/row)
  int sidx = tkn & (SEQ - 1);
  int id = ids[tkn];
  int t = threadIdx.x;
  float4 a = ((const float4*)tok)[(size_t)id * 192 + t];
  float4 b = ((const float4*)pos)[(size_t)sidx * 192 + t];
  float4 o = {a.x + b.x, a.y + b.y, a.z + b.z, a.w + b.w};
  ((float4*)x)[(size_t)tkn * 192 + t] = o;
}

// ---------------- driver ----------------
extern "C" void kernel_launch(void* const* d_in, const int* in_sizes, int n_in,
                              void* d_out, int out_size, void* d_ws, size_t ws_size,
                              hipStream_t stream)
{
  const int*   ids   = (const int*)d_in[0];
  const int*   amask = (const int*)d_in[1];
  const float* tok   = (const float*)d_in[2];
  const float* pos   = (const float*)d_in[3];
  const float* ln1w  = (const float*)d_in[4];
  const float* ln1b  = (const float*)d_in[5];
  const float* qw    = (const float*)d_in[6];
  const float* kw    = (const float*)d_in[7];
  const float* vw    = (const float*)d_in[8];
  const float* ow    = (const float*)d_in[9];
  const float* ob    = (const float*)d_in[10];
  const float* ln2w  = (const float*)d_in[11];
  const float* ln2b  = (const float*)d_in[12];
  const float* w1    = (const float*)d_in[13];
  const float* b1    = (const float*)d_in[14];
  const float* w2    = (const float*)d_in[15];
  const float* b2    = (const float*)d_in[16];
  const float* lnfw  = (const float*)d_in[17];
  const float* lnfb  = (const float*)d_in[18];
  const float* lmw   = (const float*)d_in[19];

  // ---- workspace layout (bytes), core = 37.75 MB ----
  char* ws = (char*)d_ws;
  float* x    = (float*)(ws);                   // 2048x768 f32        6,291,456
  u16*   h    = (u16*)  (ws + 6291456);         // 2048x768 bf16       3,145,728
  u16*   qkv  = (u16*)  (ws + 9437184);         // 2048x2304 bf16      9,437,184
  u16*   ab   = (u16*)  (ws + 22020096);        // attn out bf16       3,145,728
  u16*   ffb  = (u16*)  (ws + 25165824);        // 2048x3072 bf16     12,582,912 -> end 37,748,736
  // optional lm_head bf16 weight cache (cannot live in d_out: final GEMM writes
  // ALL of d_out while reading its B operand -> would race)
  u16*   wlm  = (u16*)  (ws + 37748736);        // 50257x768 bf16     77,194,752 -> end 114,943,488
  bool lmbf = ws_size >= (size_t)114943488;

  // ---- d_out scratch (411.7 MB total; all dead before final lm_head write) ----
  u16* wqkv   = (u16*)((char*)d_out + 100663296);     // 12 x 2304x768 bf16
  u16* wob    = wqkv + (size_t)NLAYER * QKVW * HDIM;  // 12 x 768x768
  u16* w1b    = wob  + (size_t)NLAYER * HDIM * HDIM;  // 12 x 3072x768
  u16* w2b    = w1b  + (size_t)NLAYER * FFI  * HDIM;  // 12 x 768x3072  -> end 270,532,608

  // ---- one-shot weight conversion fp32 -> bf16 (packed QKV), 8 elems/thread ----
  cvt_w<<<3456,  256, 0, stream>>>(qw, wqkv,           589824, 1769472, 589824, 7077888LL);
  cvt_w<<<3456,  256, 0, stream>>>(kw, wqkv + 589824,  589824, 1769472, 589824, 7077888LL);
  cvt_w<<<3456,  256, 0, stream>>>(vw, wqkv + 1179648, 589824, 1769472, 589824, 7077888LL);
  cvt_w<<<3456,  256, 0, stream>>>(ow, wob,            589824, 589824,  589824, 7077888LL);
  cvt_w<<<13824, 256, 0, stream>>>(w1, w1b,            2359296, 2359296, 2359296, 28311552LL);
  cvt_w<<<13824, 256, 0, stream>>>(w2, w2b,            2359296, 2359296, 2359296, 28311552LL);
  if (lmbf)
    cvt_w<<<18847, 256, 0, stream>>>(lmw, wlm, 0, 0, 38597376LL, 38597376LL);

  embed_k<<<NTOK, 192, 0, stream>>>(ids, tok, pos, x);

  for (int l = 0; l < NLAYER; l++) {
    ln_bf16<<<NTOK, 256, 0, stream>>>(x, ln1w + l * HDIM, ln1b + l * HDIM, h);

    // fused QKV: [2048,768] @ [2304,768]^T -> qkv [2048,2304]
    gemm_nt<u16, u16, 0, 128, 128><<<dim3(16, 18), 256, 0, stream>>>(
        h, wqkv + (size_t)l * QKVW * HDIM, qkv, nullptr,
        NTOK, QKVW, HDIM, HDIM, HDIM, QKVW, 0, 0, 0, 0, 0, 0, 1, 0, 1, 0);

    // fused flash attention: qkv -> ab (replaces transpose_v + QK^T + softmax + PV)
    flash_attn<<<dim3(SEQ / 64, BATCH * NHEAD), 256, 0, stream>>>(qkv, ab, amask);

    // proj, split-K=2, fused bias + residual: x += ab @ ow^T + ob  (atomic f32)
    gemm_nt<u16, float, 3, 128, 128><<<dim3(16, 6, 2), 256, 0, stream>>>(
        ab, wob + (size_t)l * HDIM * HDIM, x, ob + l * HDIM,
        NTOK, HDIM, HDIM, HDIM, HDIM, HDIM, 0, 0, 0, 0, 0, 0, 1, 0, 2, 0);

    ln_bf16<<<NTOK, 256, 0, stream>>>(x, ln2w + l * HDIM, ln2b + l * HDIM, h);

    // FF1 with fused bias + exact gelu -> bf16
    gemm_nt<u16, u16, 2, 128, 128><<<dim3(16, 24), 256, 0, stream>>>(
        h, w1b + (size_t)l * FFI * HDIM, ffb, b1 + l * FFI,
        NTOK, FFI, HDIM, HDIM, HDIM, FFI, 0, 0, 0, 0, 0, 0, 1, 0, 1, 0);

    // FF2, split-K=4, fused bias + residual: x += ffb @ w2^T + b2  (atomic f32)
    gemm_nt<u16, float, 3, 128, 128><<<dim3(16, 6, 4), 256, 0, stream>>>(
        ffb, w2b + (size_t)l * HDIM * FFI, x, b2 + l * HDIM,
        NTOK, HDIM, FFI, FFI, FFI, HDIM, 0, 0, 0, 0, 0, 0, 1, 0, 4, 0);
  }

  ln_bf16<<<NTOK, 256, 0, stream>>>(x, lnfw, lnfb, h);
  if (lmbf) {
    // bf16-cached lm_head weights + XCD-chunked swizzle (1-D grid, 50 panels/XCD)
    gemm_nt<u16, float, 0, 128, 128><<<6400, 256, 0, stream>>>(
        h, wlm, (float*)d_out, nullptr,
        NTOK, VOCAB, HDIM, HDIM, HDIM, VOCAB, 0, 0, 0, 0, 0, 0, 1, 0, 1, 1);
  } else {
    // fallback: fp32 weights, reg-staged + in-loop convert (same swizzle)
    gemm_nt<float, float, 0, 128, 128><<<6400, 256, 0, stream>>>(
        h, lmw, (float*)d_out, nullptr,
        NTOK, VOCAB, HDIM, HDIM, HDIM, VOCAB, 0, 0, 0, 0, 0, 0, 1, 0, 1, 1);
  }
}

// Round 8
// 3301.009 us; speedup vs baseline: 1.0384x; 1.0374x over previous
//
#include <hip/hip_runtime.h>
#include <hip/hip_bf16.h>
#include <cmath>

typedef unsigned short u16;
typedef __bf16 bf16_t;
typedef __bf16 bf16x8 __attribute__((ext_vector_type(8)));
typedef float f32x4 __attribute__((ext_vector_type(4)));

#define HDIM   768
#define NHEAD  12
#define HD     64
#define SEQ    1024
#define BATCH  2
#define NLAYER 12
#define FFI    3072
#define VOCAB  50257
#define NTOK   (BATCH*SEQ)
#define QKVW   2304   // packed q|k|v output width

__device__ inline u16 f2bf(float f) {
  bf16_t h = (bf16_t)f;                 // RNE fptrunc
  return __builtin_bit_cast(u16, h);
}

__device__ __forceinline__ void gl_lds16(const u16* g, u16* l) {
  // async global->LDS, 16B/lane; LDS dest = wave-uniform base + lane*16
  __builtin_amdgcn_global_load_lds(
      (const __attribute__((address_space(1))) unsigned int*)g,
      (__attribute__((address_space(3))) unsigned int*)l, 16, 0, 0);
}

// ---------------- batched NT GEMM: C[m,n] = sum_k A[m,k] * W[n,k] ----------------
// A bf16 via global_load_lds. W bf16 via global_load_lds, or fp32 (reg-staged + convert).
// Tile TMt x TNt, 4 waves in 2x2 grid (per-wave (TMt/2)x(TNt/2)).
// EPI: 0 = plain store (OT f32 or bf16)
//      2 = bf16( gelu(acc + bias[n]) )
//      3 = split-K residual: atomicAdd(C_f32, acc + bias[n] on first k-chunk)
// ksplit>1: blockIdx.z = K-chunk index (requires zdiv==1, K % (ksplit*BKK) == 0)
// swz!=0: 1-D grid of 6400; xcd=id&7 owns 50 contiguous N-panels (lm_head L2 locality)
// NW: min waves/EU for __launch_bounds__ (2 -> 2 blocks/CU, 3 -> 3 blocks/CU @256thr)
#define BKK 64

template<typename WT, typename OT, int EPI, int TMt, int TNt, int NW = 2>
__global__ __launch_bounds__(256, NW) void gemm_nt(
    const u16* __restrict__ A, const WT* __restrict__ W, OT* __restrict__ C,
    const float* __restrict__ bias,
    int M, int N, int K, int lda, int ldb, int ldc,
    long long aOut, long long aIn, long long bOut, long long bIn,
    long long cOut, long long cIn, int zdiv, int causal, int ksplit, int swz)
{
  constexpr int WMt = TMt / 2, WNt = TNt / 2;   // per-wave output
  constexpr int MI = WMt / 16, NJ = WNt / 16;   // 16x16 fragments per wave
  constexpr int ACH = TMt / 32;                 // 8-row staging chunks per wave
  constexpr int BCH = TNt / 32;

  __shared__ __align__(16) u16 sA[TMt * BKK];
  __shared__ __align__(16) u16 sB[TNt * BKK];

  int bx = blockIdx.x, by = blockIdx.y;
  if (swz) {
    // XCD-chunked remap: id%8 empirically selects the XCD; give each XCD a
    // contiguous span of N-panels so its L2 re-uses them. Bijective; guard tail.
    int id = blockIdx.x;
    int xcd = id & 7, j = id >> 3;
    bx = j & 15;                 // M-tile (gridM hardcoded 16: NTOK/128)
    by = xcd * 50 + (j >> 4);    // N-panel chunk of 50 per XCD
    if (by >= 393) return;
  }

  int z = blockIdx.z;
  if (zdiv > 1) {
    int zo = z / zdiv, zi = z - zo * zdiv;
    A += zo * aOut + zi * aIn;
    W += zo * bOut + zi * bIn;
    C += zo * cOut + zi * cIn;
  }
  int kt0 = 0, kend = K;
  if (ksplit > 1) {            // z indexes the K-chunk instead
    int kc = K / ksplit;
    kt0 = z * kc;
    kend = kt0 + kc;
  }
  int mt = bx * TMt;
  int nt = by * TNt;
  if (causal && nt > mt + (TMt - 1)) return;  // tile entirely above diagonal

  int t = threadIdx.x;
  int w = t >> 6, l = t & 63;
  int wm = (w >> 1) * WMt, wn = (w & 1) * WNt;
  int quad = l >> 4, mr = l & 15;

  int lrow = l >> 3;          // lane's row within 8-row staging chunk
  int lcol = (l & 7) * 8;     // lane's 8-elem k chunk

  // fp32-W staging pattern (register path)
  int arow = t >> 3, akc = (t & 7) * 8;

  f32x4 acc[MI][NJ] = {};

  for (int kt = kt0; kt < kend; kt += BKK) {
    #pragma unroll
    for (int i = 0; i < ACH; i++) {
      int row = w * (TMt / 4) + i * 8;      // wave-uniform LDS chunk base
      gl_lds16(A + (size_t)(mt + row + lrow) * lda + kt + lcol, &sA[row * BKK]);
    }
    if constexpr (sizeof(WT) == 2) {
      #pragma unroll
      for (int i = 0; i < BCH; i++) {
        int row = w * (TNt / 4) + i * 8;
        int gr = nt + row + lrow; if (gr >= N) gr = N - 1;   // per-lane clamp
        gl_lds16((const u16*)W + (size_t)gr * ldb + kt + lcol, &sB[row * BKK]);
      }
    } else {
      #pragma unroll
      for (int i = 0; i < BCH; i++) {
        int row = arow + i * 32;
        int gr = nt + row; if (gr >= N) gr = N - 1;
        const float* src = (const float*)W + (size_t)gr * ldb + kt + akc;
        float4 f0 = *(const float4*)(src);
        float4 f1 = *(const float4*)(src + 4);
        uint4 p;
        p.x = (unsigned)f2bf(f0.x) | ((unsigned)f2bf(f0.y) << 16);
        p.y = (unsigned)f2bf(f0.z) | ((unsigned)f2bf(f0.w) << 16);
        p.z = (unsigned)f2bf(f1.x) | ((unsigned)f2bf(f1.y) << 16);
        p.w = (unsigned)f2bf(f1.z) | ((unsigned)f2bf(f1.w) << 16);
        *(uint4*)(&sB[row * BKK + akc]) = p;
      }
    }
    __syncthreads();
    #pragma unroll
    for (int kk = 0; kk < BKK; kk += 32) {
      bf16x8 af[MI], bfr[NJ];
      #pragma unroll
      for (int i = 0; i < MI; i++)
        af[i] = *(const bf16x8*)(&sA[(wm + i * 16 + mr) * BKK + kk + quad * 8]);
      #pragma unroll
      for (int j = 0; j < NJ; j++)
        bfr[j] = *(const bf16x8*)(&sB[(wn + j * 16 + mr) * BKK + kk + quad * 8]);
      #pragma unroll
      for (int i = 0; i < MI; i++)
        #pragma unroll
        for (int j = 0; j < NJ; j++)
          acc[i][j] = __builtin_amdgcn_mfma_f32_16x16x32_bf16(af[i], bfr[j], acc[i][j], 0, 0, 0);
    }
    __syncthreads();
  }

  // C/D layout (m89-verified): col = lane&15, row = (lane>>4)*4 + reg
  #pragma unroll
  for (int i = 0; i < MI; i++)
    #pragma unroll
    for (int j = 0; j < NJ; j++)
      #pragma unroll
      for (int r = 0; r < 4; r++) {
        int gm = mt + wm + i * 16 + quad * 4 + r;
        int gn = nt + wn + j * 16 + mr;
        if (gn < N) {
          float v = acc[i][j][r];
          size_t idx = (size_t)gm * ldc + gn;
          if constexpr (EPI == 3) {
            float add = v + (kt0 == 0 ? bias[gn] : 0.0f);
            atomicAdd(&((float*)C)[idx], add);
          } else if constexpr (EPI == 2) {
            float u = v + bias[gn];
            float g = 0.5f * u * (1.0f + erff(u * 0.70710678118654752f));
            C[idx] = (OT)f2bf(g);
          } else {
            if constexpr (sizeof(OT) == 2) C[idx] = f2bf(v);
            else                           C[idx] = v;
          }
        }
      }
}

// ---------------- fused flash attention ----------------
// grid (16, 24): blockIdx.x = Q-block slot, blockIdx.y = z = b*NHEAD+h.
// Snake swizzle: x = (z&1) ? 15-x : x -- pairs heavy (high-MT, many causal iters)
// and light Q-blocks across the two CU occupancy rounds (384 blocks, 2/CU).
// Per block: Q[64][64] staged once; loop 64-wide K/V tiles with online softmax.
// S[m,kv] = sum_d Q[m,d]*K[kv,d]  (NT form: K needs no transpose).
// V transposed LDS->LDS for the PV NT-GEMM; sPV time-shares V-landing and P.
__global__ __launch_bounds__(256, 2) void flash_attn(
    const u16* __restrict__ qkv, u16* __restrict__ ab, const int* __restrict__ amask)
{
  __shared__ __align__(16) u16 sQ[64 * 64];
  __shared__ __align__(16) u16 sK[64 * 64];
  __shared__ __align__(16) u16 sVT[64 * 72];     // [d][kv], pad 72 vs 64: 2-way banks
  __shared__ __align__(16) u16 sPV[64 * 68];     // tileV[64][68]  <->  P[64][64]
  __shared__ u16 s_am[SEQ];

  int z  = blockIdx.y;
  int xr = blockIdx.x;
  int xm = (z & 1) ? (15 - xr) : xr;     // causal load-balance snake
  int MT = xm * 64;
  int b  = z / NHEAD, h = z - b * NHEAD;
  const u16* qbase = qkv + (size_t)(b * SEQ) * QKVW + h * HD;
  const u16* kbase = qbase + 768;
  const u16* vbase = qbase + 1536;

  int t = threadIdx.x;
  int w = t >> 6, l = t & 63;
  int quad = l >> 4, mr = l & 15;
  int lrow = l >> 3, lcol = (l & 7) * 8;
  int wm = w * 16;
  int c4 = (t & 15) * 4, r0 = t >> 4;

  // stage Q rows MT..MT+63 (per wave: 2 chunks of 8 rows)
  #pragma unroll
  for (int i = 0; i < 2; i++) {
    int row = w * 16 + i * 8;
    gl_lds16(qbase + (size_t)(MT + row + lrow) * QKVW + lcol, &sQ[row * 64]);
  }
  // stage pad-mask flags for this batch row
  {
    int4 mv = *(const int4*)(amask + b * SEQ + t * 4);
    s_am[t * 4 + 0] = (u16)(mv.x != 0);
    s_am[t * 4 + 1] = (u16)(mv.y != 0);
    s_am[t * 4 + 2] = (u16)(mv.z != 0);
    s_am[t * 4 + 3] = (u16)(mv.w != 0);
  }

  f32x4 oacc[4] = {};
  float mrun[4] = {-3.0e38f, -3.0e38f, -3.0e38f, -3.0e38f};
  float lrun[4] = {};

  for (int jt = 0; jt <= MT; jt += 64) {
    // A: issue K tile gl_lds + V tile register loads
    #pragma unroll
    for (int i = 0; i < 2; i++) {
      int row = w * 16 + i * 8;
      gl_lds16(kbase + (size_t)(jt + row + lrow) * QKVW + lcol, &sK[row * 64]);
    }
    uint2 vr[4];
    #pragma unroll
    for (int i = 0; i < 4; i++)
      vr[i] = *(const uint2*)(vbase + (size_t)(jt + r0 + i * 16) * QKVW + c4);
    __syncthreads();   // all prev-iter PV done (sPV free); K landed; V regs ready
    // D: V regs -> landing tile (padded 68)
    #pragma unroll
    for (int i = 0; i < 4; i++)
      *(uint2*)(&sPV[(r0 + i * 16) * 68 + c4]) = vr[i];
    __syncthreads();
    // F1: S = Q . K^T   (MI=1, NJ=4)
    f32x4 sacc[4] = {};
    #pragma unroll
    for (int kk = 0; kk < 64; kk += 32) {
      bf16x8 af = *(const bf16x8*)(&sQ[(wm + mr) * 64 + kk + quad * 8]);
      #pragma unroll
      for (int j = 0; j < 4; j++) {
        bf16x8 bf = *(const bf16x8*)(&sK[(j * 16 + mr) * 64 + kk + quad * 8]);
        sacc[j] = __builtin_amdgcn_mfma_f32_16x16x32_bf16(af, bf, sacc[j], 0, 0, 0);
      }
    }
    // F2: transpose landing tile -> sVT[d][kv]
    #pragma unroll
    for (int i = 0; i < 4; i++) {
      int d = r0 + i * 16;
      ushort4 o;
      o.x = sPV[(c4 + 0) * 68 + d];
      o.y = sPV[(c4 + 1) * 68 + d];
      o.z = sPV[(c4 + 2) * 68 + d];
      o.w = sPV[(c4 + 3) * 68 + d];
      *(ushort4*)(&sVT[d * 72 + c4]) = o;
    }
    __syncthreads();   // sVT ready; landing tile dead -> P may overwrite sPV
    // H: online masked softmax (scale, causal+pad mask, running max/sum)
    float sv[4][4];
    float mx[4] = {-3.0e38f, -3.0e38f, -3.0e38f, -3.0e38f};
    #pragma unroll
    for (int j = 0; j < 4; j++) {
      int colg = jt + j * 16 + mr;
      bool am = s_am[colg] != 0;
      #pragma unroll
      for (int r = 0; r < 4; r++) {
        int rowg = MT + wm + quad * 4 + r;
        float v = (am && colg <= rowg) ? sacc[j][r] * 0.125f : -1e9f;
        sv[j][r] = v;
        mx[r] = fmaxf(mx[r], v);
      }
    }
    #pragma unroll
    for (int off = 8; off > 0; off >>= 1)
      #pragma unroll
      for (int r = 0; r < 4; r++) mx[r] = fmaxf(mx[r], __shfl_xor(mx[r], off));
    float alpha[4], lsum[4];
    #pragma unroll
    for (int r = 0; r < 4; r++) {
      float mn = fmaxf(mrun[r], mx[r]);
      alpha[r] = expf(mrun[r] - mn);
      mrun[r] = mn;
      lsum[r] = 0.0f;
    }
    #pragma unroll
    for (int j = 0; j < 4; j++)
      #pragma unroll
      for (int r = 0; r < 4; r++) {
        float p = expf(sv[j][r] - mrun[r]);
        lsum[r] += p;
        sPV[(wm + quad * 4 + r) * 64 + j * 16 + mr] = f2bf(p);   // P, own-wave rows
      }
    #pragma unroll
    for (int off = 8; off > 0; off >>= 1)
      #pragma unroll
      for (int r = 0; r < 4; r++) lsum[r] += __shfl_xor(lsum[r], off);
    #pragma unroll
    for (int r = 0; r < 4; r++) {
      lrun[r] = lrun[r] * alpha[r] + lsum[r];
      #pragma unroll
      for (int j = 0; j < 4; j++) oacc[j][r] *= alpha[r];
    }
    // J: O += P . V^T   (reads own-wave P rows + shared sVT; no barrier needed)
    #pragma unroll
    for (int kk = 0; kk < 64; kk += 32) {
      bf16x8 af = *(const bf16x8*)(&sPV[(wm + mr) * 64 + kk + quad * 8]);
      #pragma unroll
      for (int j = 0; j < 4; j++) {
        bf16x8 bf = *(const bf16x8*)(&sVT[(j * 16 + mr) * 72 + kk + quad * 8]);
        oacc[j] = __builtin_amdgcn_mfma_f32_16x16x32_bf16(af, bf, oacc[j], 0, 0, 0);
      }
    }
  }
  // epilogue: normalize by running sum, write bf16
  u16* orow = ab + (size_t)(b * SEQ + MT) * HDIM + h * HD;
  #pragma unroll
  for (int r = 0; r < 4; r++) {
    float inv = 1.0f / lrun[r];
    int rowl = wm + quad * 4 + r;
    #pragma unroll
    for (int j = 0; j < 4; j++)
      orow[(size_t)rowl * HDIM + j * 16 + mr] = f2bf(oacc[j][r] * inv);
  }
}

// ---------------- weight fp32 -> bf16 pre-conversion (8 elems/thread, guarded) ----------------
__global__ __launch_bounds__(256) void cvt_w(
    const float* __restrict__ src, u16* __restrict__ dst,
    long long srcLs, long long dstLs, long long perL, long long total)
{
  long long i8 = ((long long)blockIdx.x * 256 + threadIdx.x) * 8;
  if (i8 >= total) return;
  long long l = i8 / perL;
  long long r = i8 - l * perL;
  const float4* s4 = (const float4*)(src + l * srcLs + r);
  float4 f0 = s4[0], f1 = s4[1];
  uint4 p;
  p.x = (unsigned)f2bf(f0.x) | ((unsigned)f2bf(f0.y) << 16);
  p.y = (unsigned)f2bf(f0.z) | ((unsigned)f2bf(f0.w) << 16);
  p.z = (unsigned)f2bf(f1.x) | ((unsigned)f2bf(f1.y) << 16);
  p.w = (unsigned)f2bf(f1.z) | ((unsigned)f2bf(f1.w) << 16);
  *(uint4*)(dst + l * dstLs + r) = p;
}

// ---------------- LayerNorm row kernel: fp32 in -> bf16 out ----------------
__global__ __launch_bounds__(256) void ln_bf16(
    const float* __restrict__ x, const float* __restrict__ w,
    const float* __restrict__ b, u16* __restrict__ out)
{
  __shared__ float redA[4], redB[4];
  int row = blockIdx.x;
  const float* xr = x + (size_t)row * HDIM;
  int t = threadIdx.x;
  float v0 = xr[t], v1 = xr[t + 256], v2 = xr[t + 512];
  float s  = v0 + v1 + v2;
  float s2 = v0 * v0 + v1 * v1 + v2 * v2;
  #pragma unroll
  for (int o = 32; o > 0; o >>= 1) { s += __shfl_xor(s, o); s2 += __shfl_xor(s2, o); }
  if ((t & 63) == 0) { redA[t >> 6] = s; redB[t >> 6] = s2; }
  __syncthreads();
  float S  = redA[0] + redA[1] + redA[2] + redA[3];
  float S2 = redB[0] + redB[1] + redB[2] + redB[3];
  float mean = S * (1.0f / HDIM);
  float var  = S2 * (1.0f / HDIM) - mean * mean;
  float rstd = rsqrtf(var + 1e-5f);
  u16* orow = out + (size_t)row * HDIM;
  orow[t]       = f2bf((v0 - mean) * rstd * w[t]       + b[t]);
  orow[t + 256] = f2bf((v1 - mean) * rstd * w[t + 256] + b[t + 256]);
  orow[t + 512] = f2bf((v2 - mean) * rstd * w[t + 512] + b[t + 512]);
}

// ---------------- misc ----------------
__global__ void embed_k(const int* __restrict__ ids, const float* __restrict__ tok,
                        const float* __restrict__ pos, float* __restrict__ x)
{
  int tkn = blockIdx.x;                 // 192 threads: one float4 each (768 f32/row)
  int sidx = tkn & (SEQ - 1);
  int id = ids[tkn];
  int t = threadIdx.x;
  float4 a = ((const float4*)tok)[(size_t)id * 192 + t];
  float4 b = ((const float4*)pos)[(size_t)sidx * 192 + t];
  float4 o = {a.x + b.x, a.y + b.y, a.z + b.z, a.w + b.w};
  ((float4*)x)[(size_t)tkn * 192 + t] = o;
}

// ---------------- driver ----------------
extern "C" void kernel_launch(void* const* d_in, const int* in_sizes, int n_in,
                              void* d_out, int out_size, void* d_ws, size_t ws_size,
                              hipStream_t stream)
{
  const int*   ids   = (const int*)d_in[0];
  const int*   amask = (const int*)d_in[1];
  const float* tok   = (const float*)d_in[2];
  const float* pos   = (const float*)d_in[3];
  const float* ln1w  = (const float*)d_in[4];
  const float* ln1b  = (const float*)d_in[5];
  const float* qw    = (const float*)d_in[6];
  const float* kw    = (const float*)d_in[7];
  const float* vw    = (const float*)d_in[8];
  const float* ow    = (const float*)d_in[9];
  const float* ob    = (const float*)d_in[10];
  const float* ln2w  = (const float*)d_in[11];
  const float* ln2b  = (const float*)d_in[12];
  const float* w1    = (const float*)d_in[13];
  const float* b1    = (const float*)d_in[14];
  const float* w2    = (const float*)d_in[15];
  const float* b2    = (const float*)d_in[16];
  const float* lnfw  = (const float*)d_in[17];
  const float* lnfb  = (const float*)d_in[18];
  const float* lmw   = (const float*)d_in[19];

  // ---- workspace layout (bytes), core = 37.75 MB ----
  char* ws = (char*)d_ws;
  float* x    = (float*)(ws);                   // 2048x768 f32        6,291,456
  u16*   h    = (u16*)  (ws + 6291456);         // 2048x768 bf16       3,145,728
  u16*   qkv  = (u16*)  (ws + 9437184);         // 2048x2304 bf16      9,437,184
  u16*   ab   = (u16*)  (ws + 22020096);        // attn out bf16       3,145,728
  u16*   ffb  = (u16*)  (ws + 25165824);        // 2048x3072 bf16     12,582,912 -> end 37,748,736
  // optional lm_head bf16 weight cache (cannot live in d_out: final GEMM writes
  // ALL of d_out while reading its B operand -> would race)
  u16*   wlm  = (u16*)  (ws + 37748736);        // 50257x768 bf16     77,194,752 -> end 114,943,488
  bool lmbf = ws_size >= (size_t)114943488;

  // ---- d_out scratch (411.7 MB total; all dead before final lm_head write) ----
  u16* wqkv   = (u16*)((char*)d_out + 100663296);     // 12 x 2304x768 bf16
  u16* wob    = wqkv + (size_t)NLAYER * QKVW * HDIM;  // 12 x 768x768
  u16* w1b    = wob  + (size_t)NLAYER * HDIM * HDIM;  // 12 x 3072x768
  u16* w2b    = w1b  + (size_t)NLAYER * FFI  * HDIM;  // 12 x 768x3072  -> end 270,532,608

  // ---- one-shot weight conversion fp32 -> bf16 (packed QKV), 8 elems/thread ----
  cvt_w<<<3456,  256, 0, stream>>>(qw, wqkv,           589824, 1769472, 589824, 7077888LL);
  cvt_w<<<3456,  256, 0, stream>>>(kw, wqkv + 589824,  589824, 1769472, 589824, 7077888LL);
  cvt_w<<<3456,  256, 0, stream>>>(vw, wqkv + 1179648, 589824, 1769472, 589824, 7077888LL);
  cvt_w<<<3456,  256, 0, stream>>>(ow, wob,            589824, 589824,  589824, 7077888LL);
  cvt_w<<<13824, 256, 0, stream>>>(w1, w1b,            2359296, 2359296, 2359296, 28311552LL);
  cvt_w<<<13824, 256, 0, stream>>>(w2, w2b,            2359296, 2359296, 2359296, 28311552LL);
  if (lmbf)
    cvt_w<<<18847, 256, 0, stream>>>(lmw, wlm, 0, 0, 38597376LL, 38597376LL);

  embed_k<<<NTOK, 192, 0, stream>>>(ids, tok, pos, x);

  for (int l = 0; l < NLAYER; l++) {
    ln_bf16<<<NTOK, 256, 0, stream>>>(x, ln1w + l * HDIM, ln1b + l * HDIM, h);

    // fused QKV: [2048,768] @ [2304,768]^T -> qkv [2048,2304]
    // TN=64: 576 blocks (was 288) for CU load balance; NW=3 -> 3 blocks/CU
    gemm_nt<u16, u16, 0, 128, 64, 3><<<dim3(16, 36), 256, 0, stream>>>(
        h, wqkv + (size_t)l * QKVW * HDIM, qkv, nullptr,
        NTOK, QKVW, HDIM, HDIM, HDIM, QKVW, 0, 0, 0, 0, 0, 0, 1, 0, 1, 0);

    // fused flash attention: qkv -> ab
    flash_attn<<<dim3(SEQ / 64, BATCH * NHEAD), 256, 0, stream>>>(qkv, ab, amask);

    // proj, split-K=4 (384 blocks), fused bias + residual: x += ab @ ow^T + ob
    gemm_nt<u16, float, 3, 128, 128><<<dim3(16, 6, 4), 256, 0, stream>>>(
        ab, wob + (size_t)l * HDIM * HDIM, x, ob + l * HDIM,
        NTOK, HDIM, HDIM, HDIM, HDIM, HDIM, 0, 0, 0, 0, 0, 0, 1, 0, 4, 0);

    ln_bf16<<<NTOK, 256, 0, stream>>>(x, ln2w + l * HDIM, ln2b + l * HDIM, h);

    // FF1 with fused bias + exact gelu -> bf16. TN=64: 768 blocks = 3.0/CU uniform
    gemm_nt<u16, u16, 2, 128, 64, 3><<<dim3(16, 48), 256, 0, stream>>>(
        h, w1b + (size_t)l * FFI * HDIM, ffb, b1 + l * FFI,
        NTOK, FFI, HDIM, HDIM, HDIM, FFI, 0, 0, 0, 0, 0, 0, 1, 0, 1, 0);

    // FF2, split-K=6 (576 blocks), fused bias + residual: x += ffb @ w2^T + b2
    gemm_nt<u16, float, 3, 128, 128><<<dim3(16, 6, 6), 256, 0, stream>>>(
        ffb, w2b + (size_t)l * HDIM * FFI, x, b2 + l * HDIM,
        NTOK, HDIM, FFI, FFI, FFI, HDIM, 0, 0, 0, 0, 0, 0, 1, 0, 6, 0);
  }

  ln_bf16<<<NTOK, 256, 0, stream>>>(x, lnfw, lnfb, h);
  if (lmbf) {
    // bf16-cached lm_head weights + XCD-chunked swizzle (1-D grid, 50 panels/XCD)
    gemm_nt<u16, float, 0, 128, 128><<<6400, 256, 0, stream>>>(
        h, wlm, (float*)d_out, nullptr,
        NTOK, VOCAB, HDIM, HDIM, HDIM, VOCAB, 0, 0, 0, 0, 0, 0, 1, 0, 1, 1);
  } else {
    // fallback: fp32 weights, reg-staged + in-loop convert (same swizzle)
    gemm_nt<float, float, 0, 128, 128><<<6400, 256, 0, stream>>>(
        h, lmw, (float*)d_out, nullptr,
        NTOK, VOCAB, HDIM, HDIM, HDIM, VOCAB, 0, 0, 0, 0, 0, 0, 1, 0, 1, 1);
  }
}